// Round 1
// 696.051 us; speedup vs baseline: 1.1140x; 1.1140x over previous
//
#include <hip/hip_runtime.h>
#include <math.h>

// Problem: x [8,128,256,256] f32, weights [128] f32.
// out[b,i,h,w] = (softmax(weights)*128)[rank(i within column)] * rsqrt(x^2+eps)
// rank[i] = #{j<i: x[j] >= x[i]} + #{j>i: x[j] > x[i]}  (stable descending rank)
//
// R3: theory = carry-class VALU (v_cmp->sgpr + v_addc) runs ~half rate and the
// paired asm pins a hazard-prone schedule. Replace with pure int arithmetic on
// monotonic keys: t=ka-kb; s=t>>31; ra-=s; rb+=s  (4 plain ops per UNORDERED
// pair, both sides). All-symmetric coverage: each wave = own 32x32 diagonal +
// 1.5 cross jobs; partial ranks merged via u8-packed LDS atomics (ranks<=127,
// bytes never carry). LDS = 32K keys + 8K counts = 40KB exactly -> 4 blocks/CU.
// Weight table lives in registers (per-wave softmax), gathered by __shfl.

#define Q    128
#define TCOL 64
#define HW   65536
#define EPSF 1e-6f

// monotonic float-bits <-> signed int key; order- and tie-preserving involution
__device__ __forceinline__ int f2key(int b) {
    return b ^ (int)(((unsigned)(b >> 31)) >> 1);
}

__launch_bounds__(256, 4)
__global__ void rank_weight_kernel(const float* __restrict__ x,
                                   const float* __restrict__ weights,
                                   float* __restrict__ out) {
    __shared__ int      lds_k[Q][TCOL];       // 32 KB: monotonic keys
    __shared__ unsigned lds_cnt[Q / 4][TCOL]; // 8 KB: 4 rank-bytes per word

    const int tid = threadIdx.x;
    const int g   = blockIdx.x;
    const int b   = g >> 10;               // 1024 groups of 64 hw per batch
    const int hw0 = (g & 1023) << 6;
    const float* xb = x   + (size_t)b * Q * HW + hw0;
    float*       ob = out + (size_t)b * Q * HW + hw0;

    // ---- stage 128x64 tile as keys: 2048 float4, coalesced ----
    for (int f = tid; f < Q * (TCOL / 4); f += 256) {
        const int r = f >> 4;
        const int p = (f & 15) << 2;
        float4 v = *reinterpret_cast<const float4*>(xb + (size_t)r * HW + p);
        int4 k;
        k.x = f2key(__float_as_int(v.x));
        k.y = f2key(__float_as_int(v.y));
        k.z = f2key(__float_as_int(v.z));
        k.w = f2key(__float_as_int(v.w));
        *reinterpret_cast<int4*>(&lds_k[r][p]) = k;
    }
    // ---- zero the packed count accumulators (512 uint4) ----
    {
        uint4 z = {0u, 0u, 0u, 0u};
        for (int i = tid; i < (Q / 4) * TCOL / 4; i += 256)
            reinterpret_cast<uint4*>(&lds_cnt[0][0])[i] = z;
    }

    const int wave = tid >> 6;
    const int c    = tid & 63;

    // ---- softmax(weights)*128 per wave, kept in registers (no LDS) ----
    float w0s, w1s;
    {
        float a0 = weights[c], a1 = weights[c + 64];
        float m = fmaxf(a0, a1);
        #pragma unroll
        for (int off = 32; off; off >>= 1) m = fmaxf(m, __shfl_xor(m, off, 64));
        float e0 = __expf(a0 - m), e1 = __expf(a1 - m);
        float s = e0 + e1;
        #pragma unroll
        for (int off = 32; off; off >>= 1) s += __shfl_xor(s, off, 64);
        const float scale = 128.0f / s;
        w0s = e0 * scale;   // weight for rank c
        w1s = e1 * scale;   // weight for rank c+64
    }
    __syncthreads();

    // ---- job 1: diagonal 32x32 block, rows [B0, B0+32), symmetric ----
    {
        const int B0 = wave << 5;
        int kD[32], cD[32];
        #pragma unroll
        for (int u = 0; u < 32; ++u) kD[u] = lds_k[B0 + u][c];
        #pragma unroll
        for (int u = 0; u < 32; ++u) cD[u] = u;   // bias: u earlier partners
        #pragma unroll
        for (int a = 0; a < 32; ++a) {
            #pragma unroll
            for (int e = a + 1; e < 32; ++e) {
                const int t = kD[a] - kD[e];
                const int s = t >> 31;            // -1 iff k[a] < k[e]
                cD[a] -= s;                       // += [k_e >  k_a]
                cD[e] += s;                       // += [k_a >= k_e] - 1 (bias pre-added)
            }
        }
        #pragma unroll
        for (int m = 0; m < 8; ++m) {
            unsigned wv = (unsigned)cD[4 * m]            | ((unsigned)cD[4 * m + 1] << 8)
                        | ((unsigned)cD[4 * m + 2] << 16) | ((unsigned)cD[4 * m + 3] << 24);
            atomicAdd(&lds_cnt[(B0 >> 2) + m][c], wv);
        }
    }

    // ---- jobs 2+3: symmetric cross-block counting ----
    // X rows all have smaller global index than Y rows (X0 < Y0 guaranteed).
    auto cross_job = [&](const int X0, const int XR, const int Y0) {
        int kY[32], cY[32];
        #pragma unroll
        for (int u = 0; u < 32; ++u) kY[u] = lds_k[Y0 + u][c];
        #pragma unroll
        for (int u = 0; u < 32; ++u) cY[u] = XR;  // bias: XR earlier partners
        for (int m = 0; m < (XR >> 2); ++m) {
            const int xr = X0 + (m << 2);
            int kx0 = lds_k[xr + 0][c];
            int kx1 = lds_k[xr + 1][c];
            int kx2 = lds_k[xr + 2][c];
            int kx3 = lds_k[xr + 3][c];
            int cx0 = 0, cx1 = 0, cx2 = 0, cx3 = 0;
            #pragma unroll
            for (int j = 0; j < 32; ++j) {
                const int ky = kY[j];
                const int s0 = (kx0 - ky) >> 31; cx0 -= s0;
                const int s1 = (kx1 - ky) >> 31; cx1 -= s1;
                const int s2 = (kx2 - ky) >> 31; cx2 -= s2;
                const int s3 = (kx3 - ky) >> 31; cx3 -= s3;
                cY[j] += (s0 + s1) + (s2 + s3);
            }
            unsigned wv = (unsigned)cx0         | ((unsigned)cx1 << 8)
                        | ((unsigned)cx2 << 16) | ((unsigned)cx3 << 24);
            atomicAdd(&lds_cnt[xr >> 2][c], wv);
        }
        #pragma unroll
        for (int n = 0; n < 8; ++n) {
            unsigned wv = (unsigned)cY[4 * n]            | ((unsigned)cY[4 * n + 1] << 8)
                        | ((unsigned)cY[4 * n + 2] << 16) | ((unsigned)cY[4 * n + 3] << 24);
            atomicAdd(&lds_cnt[(Y0 >> 2) + n][c], wv);
        }
    };

    // full cross jobs: w0:(0,1) w1:(1,2) w2:(2,3) w3:(0,3)
    const int cXb = (wave == 3) ? 0  : (wave << 5);
    const int cYb = (wave == 3) ? 96 : ((wave << 5) + 32);
    cross_job(cXb, 32, cYb);

    // half cross jobs: (0,2) split w0/w1 by X halves; (1,3) split w2/w3
    const int hXb = wave << 4;                 // 0,16,32,48
    const int hYb = (wave < 2) ? 64 : 96;
    cross_job(hXb, 16, hYb);

    __syncthreads();

    // ---- epilogue: extract ranks, gather weight via shfl, coalesced store ----
    const int R0 = wave << 5;
    #pragma unroll
    for (int mw = 0; mw < 8; ++mw) {
        const unsigned wv = lds_cnt[(R0 >> 2) + mw][c];
        #pragma unroll
        for (int q = 0; q < 4; ++q) {
            const int   r    = R0 + (mw << 2) + q;
            const int   rank = (wv >> (q << 3)) & 0xFF;
            const int   k    = lds_k[r][c];
            const float xv   = __int_as_float(f2key(k));  // involution: key->bits
            const int   rl   = rank & 63;
            const float wa   = __shfl(w0s, rl, 64);
            const float wb   = __shfl(w1s, rl, 64);
            const float wt   = (rank & 64) ? wb : wa;
            ob[(size_t)r * HW + c] = wt * rsqrtf(xv * xv + EPSF);
        }
    }
}

extern "C" void kernel_launch(void* const* d_in, const int* in_sizes, int n_in,
                              void* d_out, int out_size, void* d_ws, size_t ws_size,
                              hipStream_t stream) {
    const float* x  = (const float*)d_in[0];
    const float* wt = (const float*)d_in[1];
    float* out      = (float*)d_out;

    dim3 grid(8192), block(256);   // 524288 columns / 64 per block
    hipLaunchKernelGGL(rank_weight_kernel, grid, block, 0, stream, x, wt, out);
}

// Round 2
// 695.289 us; speedup vs baseline: 1.1152x; 1.0011x over previous
//
#include <hip/hip_runtime.h>
#include <math.h>

// Problem: x [8,128,256,256] f32, weights [128] f32.
// out[b,i,h,w] = (softmax(weights)*128)[rank(i within column)] * rsqrt(x^2+eps)
// rank[i] = #{j<i: x[j] >= x[i]} + #{j>i: x[j] > x[i]}  (stable descending rank)
//
// R4: R3's sign-trick pair math was right (3.75 plain VALU ops per unordered
// pair, both sides) but kY[32]+cY[32] needed ~85 live VGPRs vs 64 allocated ->
// scratch spill (WRITE_SIZE +34MB, FETCH +15MB). Restructure to 16-row Y-chunks
// and 16-row sub-diagonals so peak live regs ~56: same op count, no spill.
// Packed u8 rank bytes in LDS merged with ds_add atomics (all partials
// non-negative, final ranks <= 127 -> bytes never carry across lanes).

#define Q    128
#define TCOL 64
#define HW   65536
#define EPSF 1e-6f

// monotonic float-bits <-> signed int key; order- and tie-preserving involution
__device__ __forceinline__ int f2key(int b) {
    return b ^ (int)(((unsigned)(b >> 31)) >> 1);
}

__device__ __forceinline__ unsigned pack4(int a, int b, int c, int d) {
    return (unsigned)a | ((unsigned)b << 8) | ((unsigned)c << 16) | ((unsigned)d << 24);
}

// Cross tile: X rows [X0, X0+4*NQ) all earlier than Y rows [Y0, Y0+16).
// For x: count [k_y > k_x]; for y: count [k_x >= k_y] (bias NQ*4 folded in).
// s = (kx-ky)>>31 is -1 iff ky > kx. cx -= s; cY += s (from bias).
__device__ __forceinline__ void tile16(int (*lk)[TCOL], unsigned (*lc)[TCOL],
                                       const int c, const int X0, const int NQ,
                                       const int Y0) {
    int kY[16], cY[16];
    #pragma unroll
    for (int u = 0; u < 16; ++u) kY[u] = lk[Y0 + u][c];
    #pragma unroll
    for (int u = 0; u < 16; ++u) cY[u] = NQ << 2;   // bias: one per X partner
    for (int m = 0; m < NQ; ++m) {
        const int xr  = X0 + (m << 2);
        const int kx0 = lk[xr + 0][c];
        const int kx1 = lk[xr + 1][c];
        const int kx2 = lk[xr + 2][c];
        const int kx3 = lk[xr + 3][c];
        int cx0 = 0, cx1 = 0, cx2 = 0, cx3 = 0;
        #pragma unroll
        for (int j = 0; j < 16; ++j) {
            const int ky = kY[j];
            const int s0 = (kx0 - ky) >> 31; cx0 -= s0;
            const int s1 = (kx1 - ky) >> 31; cx1 -= s1;
            const int s2 = (kx2 - ky) >> 31; cx2 -= s2;
            const int s3 = (kx3 - ky) >> 31; cx3 -= s3;
            cY[j] += (s0 + s1) + (s2 + s3);
        }
        atomicAdd(&lc[xr >> 2][c], pack4(cx0, cx1, cx2, cx3));
    }
    #pragma unroll
    for (int n = 0; n < 4; ++n)
        atomicAdd(&lc[(Y0 >> 2) + n][c],
                  pack4(cY[4 * n], cY[4 * n + 1], cY[4 * n + 2], cY[4 * n + 3]));
}

// In-register 16x16 sub-diagonal: 120 unordered pairs, 4 ops each.
// a earlier, e later: cD[a] -= s (counts later-greater); cD[e] += s with
// bias e_local (counts earlier-ge). All partials stay in [0,15].
__device__ __forceinline__ void subdiag16(int (*lk)[TCOL], unsigned (*lc)[TCOL],
                                          const int c, const int B0) {
    int kD[16], cD[16];
    #pragma unroll
    for (int u = 0; u < 16; ++u) kD[u] = lk[B0 + u][c];
    #pragma unroll
    for (int u = 0; u < 16; ++u) cD[u] = u;
    #pragma unroll
    for (int a = 0; a < 16; ++a) {
        #pragma unroll
        for (int e = a + 1; e < 16; ++e) {
            const int s = (kD[a] - kD[e]) >> 31;
            cD[a] -= s;
            cD[e] += s;
        }
    }
    #pragma unroll
    for (int n = 0; n < 4; ++n)
        atomicAdd(&lc[(B0 >> 2) + n][c],
                  pack4(cD[4 * n], cD[4 * n + 1], cD[4 * n + 2], cD[4 * n + 3]));
}

__launch_bounds__(256, 4)
__global__ void rank_weight_kernel(const float* __restrict__ x,
                                   const float* __restrict__ weights,
                                   float* __restrict__ out) {
    __shared__ int      lds_k[Q][TCOL];       // 32 KB: monotonic keys
    __shared__ unsigned lds_cnt[Q / 4][TCOL]; // 8 KB: 4 rank-bytes per word

    const int tid = threadIdx.x;
    const int g   = blockIdx.x;
    const int b   = g >> 10;               // 1024 groups of 64 hw per batch
    const int hw0 = (g & 1023) << 6;
    const float* xb = x   + (size_t)b * Q * HW + hw0;
    float*       ob = out + (size_t)b * Q * HW + hw0;

    // ---- stage 128x64 tile as keys: 2048 float4, coalesced ----
    for (int f = tid; f < Q * (TCOL / 4); f += 256) {
        const int r = f >> 4;
        const int p = (f & 15) << 2;
        float4 v = *reinterpret_cast<const float4*>(xb + (size_t)r * HW + p);
        int4 k;
        k.x = f2key(__float_as_int(v.x));
        k.y = f2key(__float_as_int(v.y));
        k.z = f2key(__float_as_int(v.z));
        k.w = f2key(__float_as_int(v.w));
        *reinterpret_cast<int4*>(&lds_k[r][p]) = k;
    }
    // ---- zero the packed count accumulators (512 uint4) ----
    {
        uint4 z = {0u, 0u, 0u, 0u};
        for (int i = tid; i < (Q / 4) * TCOL / 4; i += 256)
            reinterpret_cast<uint4*>(&lds_cnt[0][0])[i] = z;
    }

    const int wave = tid >> 6;
    const int c    = tid & 63;

    // ---- softmax(weights)*128 per wave, kept in registers (no LDS) ----
    float w0s, w1s;
    {
        float a0 = weights[c], a1 = weights[c + 64];
        float m = fmaxf(a0, a1);
        #pragma unroll
        for (int off = 32; off; off >>= 1) m = fmaxf(m, __shfl_xor(m, off, 64));
        float e0 = __expf(a0 - m), e1 = __expf(a1 - m);
        float s = e0 + e1;
        #pragma unroll
        for (int off = 32; off; off >>= 1) s += __shfl_xor(s, off, 64);
        const float scale = 128.0f / s;
        w0s = e0 * scale;   // weight for rank c
        w1s = e1 * scale;   // weight for rank c+64
    }
    __syncthreads();

    // ---- per-wave job schedule (same pair partition as R3, chunked) ----
    const int B0 = wave << 5;

    // diagonal 32 rows: two 16-row sub-diagonals + one 16x16 cross tile
    subdiag16(lds_k, lds_cnt, c, B0);
    subdiag16(lds_k, lds_cnt, c, B0 + 16);
    tile16(lds_k, lds_cnt, c, B0, 4, B0 + 16);

    // full cross jobs (32x32): w0:(0,1) w1:(1,2) w2:(2,3) w3:(0,3)
    const int cXb = (wave == 3) ? 0  : (wave << 5);
    const int cYb = (wave == 3) ? 96 : ((wave << 5) + 32);
    tile16(lds_k, lds_cnt, c, cXb, 8, cYb);
    tile16(lds_k, lds_cnt, c, cXb, 8, cYb + 16);

    // half cross jobs (16x32): (0,2) split w0/w1 by X halves; (1,3) w2/w3
    const int hXb = wave << 4;                 // 0,16,32,48
    const int hYb = (wave < 2) ? 64 : 96;
    tile16(lds_k, lds_cnt, c, hXb, 4, hYb);
    tile16(lds_k, lds_cnt, c, hXb, 4, hYb + 16);

    __syncthreads();

    // ---- epilogue: extract ranks, gather weight via shfl, coalesced store ----
    const int R0 = wave << 5;
    #pragma unroll
    for (int mw = 0; mw < 8; ++mw) {
        const unsigned wv = lds_cnt[(R0 >> 2) + mw][c];
        #pragma unroll
        for (int q = 0; q < 4; ++q) {
            const int   r    = R0 + (mw << 2) + q;
            const int   rank = (wv >> (q << 3)) & 0xFF;
            const int   k    = lds_k[r][c];
            const float xv   = __int_as_float(f2key(k));  // involution: key->bits
            const int   rl   = rank & 63;
            const float wa   = __shfl(w0s, rl, 64);
            const float wb   = __shfl(w1s, rl, 64);
            const float wt   = (rank & 64) ? wb : wa;
            ob[(size_t)r * HW + c] = wt * rsqrtf(xv * xv + EPSF);
        }
    }
}

extern "C" void kernel_launch(void* const* d_in, const int* in_sizes, int n_in,
                              void* d_out, int out_size, void* d_ws, size_t ws_size,
                              hipStream_t stream) {
    const float* x  = (const float*)d_in[0];
    const float* wt = (const float*)d_in[1];
    float* out      = (float*)d_out;

    dim3 grid(8192), block(256);   // 524288 columns / 64 per block
    hipLaunchKernelGGL(rank_weight_kernel, grid, block, 0, stream, x, wt, out);
}